// Round 14
// baseline (29.293 us; speedup 1.0000x reference)
//
#include <hip/hip_runtime.h>

#define NA 3
#define NCLS 3
#define NB 12
#define BATCH 128

#define NH 2911104              // total cells across the 3 scales, whole batch
#define OL_END 138624           // cell idx < this -> oL
#define OM_END 693120           // + medium
#define B1_F4 277248            // float4 boundary L/M
#define B2_F4 1386240           // float4 boundary M/S

#define CORR_BLOCKS 96          // 4 (scale,image) pairs per block, one per WAVE
#define SITER 16
#define STREAM_BLOCKS 711       // ceil(NH / (256*16))
#define UNITS (CORR_BLOCKS + STREAM_BLOCKS)   // 807

// Anchors per scale (already divided by stride)
__device__ __constant__ float AWc[3][3] = {{3.625f, 4.875f, 11.65625f},
                                           {1.875f, 3.875f, 3.6875f},
                                           {1.25f,  2.0f,   4.125f}};
__device__ __constant__ float AHc[3][3] = {{2.8125f, 6.1875f, 10.1875f},
                                           {3.8125f, 2.8125f, 7.4375f},
                                           {1.625f,  3.75f,   2.875f}};

__device__ __forceinline__ float safelog(float x) {
    return fmaxf(__logf(x), -100.0f);
}

// Correction wave: one (scale, image) per wave, lanes 0..35 = (box, anchor).
// Base sum counts -0.5*safelog(1-conf) for EVERY cell; corrections:
//   + 0.5*safelog(1-conf) once per unique cleared cell (noobj -> 0)
//   + obj terms once per unique obj cell (last-box-wins = scatter order)
template <int G, int S>
__device__ __forceinline__ float corr_body(int b, int l,
                                           const float* __restrict__ outp,
                                           const float* __restrict__ boxes,
                                           const int* __restrict__ labels) {
    constexpr int GG = G * G;
    constexpr int CELLS = NA * GG;
    const int n = l / 3, a = l - n * 3;
    const bool active = (l < 36);
    const int nn = active ? n : 0;

    float4 bx = ((const float4*)boxes)[b * NB + nn];
    int lab = labels[b * NB + nn];
    bool valid = active && (lab < NCLS);

    float bw = bx.z * (float)G, bh = bx.w * (float)G;
    int gi = min(max((int)(bx.x * (float)G), 0), G - 1);
    int gj = min(max((int)(bx.y * (float)G), 0), G - 1);

    float iou[3]; int best = 0; float bi = -1.0f;
#pragma unroll
    for (int aa = 0; aa < 3; aa++) {
        float aw = AWc[S][aa], ah = AHc[S][aa];
        float inter = fminf(aw, bw) * fminf(ah, bh);
        float uni = aw * ah + 1e-16f + bw * bh - inter;
        iou[aa] = inter / uni;
        if (iou[aa] > bi) { bi = iou[aa]; best = aa; }  // first max = argmax
    }
    bool cleared = valid && (iou[a] > 0.5f || a == best);
    bool isobj   = valid && (a == best);

    unsigned key = (unsigned)(a * GG + gj * G + gi);    // cell index in b-slice
    unsigned v = key | (cleared ? 0x100000u : 0u) | (isobj ? 0x200000u : 0u);

    bool dupc = false, notwin = false;
#pragma unroll
    for (int j = 0; j < 36; j++) {
        unsigned vj = (unsigned)__shfl((int)v, j);      // intra-wave
        bool same = ((vj ^ v) & 0xFFFFFu) == 0u;
        dupc   = dupc   || (same && (vj & 0x100000u) && j < l);  // earlier lane owns it
        notwin = notwin || (same && (vj & 0x200000u) && j > l);  // later box wins obj
    }

    float corr = 0.0f;
    const float* cellp = outp + ((size_t)b * CELLS + key) * 8;

    if (cleared && !dupc) {
        float conf = cellp[4];
        corr += 0.5f * safelog(1.0f - conf);   // cancel base noobj term
    }
    if (isobj && !notwin) {
        float4 q0 = *(const float4*)cellp;
        float4 q1 = *(const float4*)(cellp + 4);
        float aw = AWc[S][a], ah = AHc[S][a];
        float tw = __logf(bw / aw + 1e-16f);
        float th = __logf(bh / ah + 1e-16f);
        float px = q0.x - floorf(q0.x);
        float py = q0.y - floorf(q0.y);
        float pw = __logf(q0.z / aw + 1e-16f);
        float ph = __logf(q0.w / ah + 1e-16f);
        float dw = pw - tw, dh = ph - th;
        float conf = q1.x;
        corr += px * px + py * py + dw * dw + dh * dh;
        corr -= 5.0f * safelog(conf);                       // OBJ_SCALE * bce(conf,1)
        corr -= (lab == 0) ? safelog(q1.y) : safelog(1.0f - q1.y);
        corr -= (lab == 1) ? safelog(q1.z) : safelog(1.0f - q1.z);
        corr -= (lab == 2) ? safelog(q1.w) : safelog(1.0f - q1.w);
    }
    return corr;
}

__launch_bounds__(256)
__global__ void fused_loss(const float* __restrict__ oL,
                           const float* __restrict__ oM,
                           const float* __restrict__ oS,
                           const float* __restrict__ boxes,
                           const int* __restrict__ labels,
                           float* __restrict__ out)
{
    __shared__ float red4[4];
    const int u = blockIdx.x;
    const int tid = threadIdx.x;
    const int w = tid >> 6;
    const int l = tid & 63;
    float acc = 0.0f;

    if (u < CORR_BLOCKS) {
        // one (scale,image) per wave; scattered/latency-bound, overlaps streaming
        int p = u * 4 + w;           // 0..383
        int s = p >> 7, b = p & 127;
        if      (s == 0) acc = corr_body<19, 0>(b, l, oL, boxes, labels);
        else if (s == 1) acc = corr_body<38, 1>(b, l, oM, boxes, labels);
        else             acc = corr_body<76, 2>(b, l, oS, boxes, labels);
    } else {
        // streaming: conf dword only (4B of each 32B cell; every line touched anyway)
        // 16 independent loads in flight per thread; bounds recomputed (no os[] regs)
        const int base = (u - CORR_BLOCKS) * (256 * SITER) + tid;
        float cv[SITER];
#pragma unroll
        for (int k = 0; k < SITER; k++) {
            int o = base + k * 256;
            int oc = (o < NH) ? o : (NH - 1);
            int f = 2 * oc + 1;                 // odd f4 = [conf, c0, c1, c2]
            const float* p; int off;
            if (oc < OL_END)      { p = oL; off = f; }
            else if (oc < OM_END) { p = oM; off = f - B1_F4; }
            else                  { p = oS; off = f - B2_F4; }
            cv[k] = p[(size_t)off * 4];         // conf
        }
#pragma unroll
        for (int k = 0; k < SITER; k++) {
            float t = -0.5f * safelog(1.0f - cv[k]);   // NOOBJ_SCALE*bce(conf,0)
            acc += ((base + k * 256) < NH) ? t : 0.0f;
        }
    }

    // wave butterfly (no barrier), one LDS step, then ONE fire-and-forget atomic
    // per block (device-scope; no return -> no ack wait, pipelines in TCC)
#pragma unroll
    for (int d = 1; d < 64; d <<= 1)
        acc += __shfl_xor(acc, d);
    if (l == 0) red4[w] = acc;
    __syncthreads();
    if (tid == 0)
        atomicAdd(out, ((red4[0] + red4[1]) + (red4[2] + red4[3])) * (1.0f / (float)BATCH));
}

extern "C" void kernel_launch(void* const* d_in, const int* in_sizes, int n_in,
                              void* d_out, int out_size, void* d_ws, size_t ws_size,
                              hipStream_t stream) {
    const float* oL     = (const float*)d_in[0];
    const float* oM     = (const float*)d_in[1];
    const float* oS     = (const float*)d_in[2];
    const float* boxes  = (const float*)d_in[3];
    const int*   labels = (const int*)d_in[4];

    // zero the 4-byte accumulator each call (graph-safe async memset)
    hipMemsetAsync(d_out, 0, sizeof(float), stream);
    fused_loss<<<UNITS, 256, 0, stream>>>(oL, oM, oS, boxes, labels, (float*)d_out);
}

// Round 15
// 22.385 us; speedup vs baseline: 1.3086x; 1.3086x over previous
//
#include <hip/hip_runtime.h>

#define NA 3
#define NCLS 3
#define NB 12
#define BATCH 128

#define OL_CELLS 138624
#define OM_CELLS 554496
#define OS_CELLS 2217984

#define CORR_BLOCKS 96          // 4 (scale,image) pairs per block, one per WAVE
#define SITER 16
#define CPB (256 * SITER)       // 4096 cells per streaming block
#define LBLK 34                 // ceil(OL_CELLS/CPB)
#define MBLK 136                // ceil(OM_CELLS/CPB)
#define SBLK 542                // ceil(OS_CELLS/CPB)
#define STREAM_BLOCKS (LBLK + MBLK + SBLK)    // 712
#define UNITS (CORR_BLOCKS + STREAM_BLOCKS)   // 808

// Anchors per scale (already divided by stride)
__device__ __constant__ float AWc[3][3] = {{3.625f, 4.875f, 11.65625f},
                                           {1.875f, 3.875f, 3.6875f},
                                           {1.25f,  2.0f,   4.125f}};
__device__ __constant__ float AHc[3][3] = {{2.8125f, 6.1875f, 10.1875f},
                                           {3.8125f, 2.8125f, 7.4375f},
                                           {1.625f,  3.75f,   2.875f}};

__device__ __forceinline__ float safelog(float x) {
    return fmaxf(__logf(x), -100.0f);
}

// Correction wave: one (scale, image) per wave, lanes 0..35 = (box, anchor).
// Base sum counts -0.5*safelog(1-conf) for EVERY cell; corrections:
//   + 0.5*safelog(1-conf) once per unique cleared cell (noobj -> 0)
//   + obj terms once per unique obj cell (last-box-wins = scatter order)
template <int G, int S>
__device__ __forceinline__ float corr_body(int b, int l,
                                           const float* __restrict__ outp,
                                           const float* __restrict__ boxes,
                                           const int* __restrict__ labels) {
    constexpr int GG = G * G;
    constexpr int CELLS = NA * GG;
    const int n = l / 3, a = l - n * 3;
    const bool active = (l < 36);
    const int nn = active ? n : 0;

    float4 bx = ((const float4*)boxes)[b * NB + nn];
    int lab = labels[b * NB + nn];
    bool valid = active && (lab < NCLS);

    float bw = bx.z * (float)G, bh = bx.w * (float)G;
    int gi = min(max((int)(bx.x * (float)G), 0), G - 1);
    int gj = min(max((int)(bx.y * (float)G), 0), G - 1);

    float iou[3]; int best = 0; float bi = -1.0f;
#pragma unroll
    for (int aa = 0; aa < 3; aa++) {
        float aw = AWc[S][aa], ah = AHc[S][aa];
        float inter = fminf(aw, bw) * fminf(ah, bh);
        float uni = aw * ah + 1e-16f + bw * bh - inter;
        iou[aa] = inter / uni;
        if (iou[aa] > bi) { bi = iou[aa]; best = aa; }  // first max = argmax
    }
    bool cleared = valid && (iou[a] > 0.5f || a == best);
    bool isobj   = valid && (a == best);

    unsigned key = (unsigned)(a * GG + gj * G + gi);    // cell index in b-slice
    unsigned v = key | (cleared ? 0x100000u : 0u) | (isobj ? 0x200000u : 0u);

    bool dupc = false, notwin = false;
#pragma unroll
    for (int j = 0; j < 36; j++) {
        unsigned vj = (unsigned)__shfl((int)v, j);      // intra-wave
        bool same = ((vj ^ v) & 0xFFFFFu) == 0u;
        dupc   = dupc   || (same && (vj & 0x100000u) && j < l);  // earlier lane owns it
        notwin = notwin || (same && (vj & 0x200000u) && j > l);  // later box wins obj
    }

    float corr = 0.0f;
    const float* cellp = outp + ((size_t)b * CELLS + key) * 8;

    if (cleared && !dupc) {
        float conf = cellp[4];
        corr += 0.5f * safelog(1.0f - conf);   // cancel base noobj term
    }
    if (isobj && !notwin) {
        float4 q0 = *(const float4*)cellp;
        float4 q1 = *(const float4*)(cellp + 4);
        float aw = AWc[S][a], ah = AHc[S][a];
        float tw = __logf(bw / aw + 1e-16f);
        float th = __logf(bh / ah + 1e-16f);
        float px = q0.x - floorf(q0.x);
        float py = q0.y - floorf(q0.y);
        float pw = __logf(q0.z / aw + 1e-16f);
        float ph = __logf(q0.w / ah + 1e-16f);
        float dw = pw - tw, dh = ph - th;
        float conf = q1.x;
        corr += px * px + py * py + dw * dw + dh * dh;
        corr -= 5.0f * safelog(conf);                       // OBJ_SCALE * bce(conf,1)
        corr -= (lab == 0) ? safelog(q1.y) : safelog(1.0f - q1.y);
        corr -= (lab == 1) ? safelog(q1.z) : safelog(1.0f - q1.z);
        corr -= (lab == 2) ? safelog(q1.w) : safelog(1.0f - q1.w);
    }
    return corr;
}

__launch_bounds__(256)
__global__ void fused_loss(const float* __restrict__ oL,
                           const float* __restrict__ oM,
                           const float* __restrict__ oS,
                           const float* __restrict__ boxes,
                           const int* __restrict__ labels,
                           float* __restrict__ partials)
{
    __shared__ float red4[4];
    const int u = blockIdx.x;
    const int tid = threadIdx.x;
    const int w = tid >> 6;
    const int l = tid & 63;
    float acc = 0.0f;

    if (u < CORR_BLOCKS) {
        // one (scale,image) per wave; scattered/latency-bound, overlaps streaming
        int p = u * 4 + w;           // 0..383
        int s = p >> 7, b = p & 127;
        if      (s == 0) acc = corr_body<19, 0>(b, l, oL, boxes, labels);
        else if (s == 1) acc = corr_body<38, 1>(b, l, oM, boxes, labels);
        else             acc = corr_body<76, 2>(b, l, oS, boxes, labels);
    } else {
        // streaming: block statically bound to ONE tensor (uniform select);
        // conf dword per cell (4B of each 32B cell; every line touched anyway)
        int sb = u - CORR_BLOCKS;
        const float* pb; int lb, ncell;
        if (sb < LBLK)              { pb = oL; lb = sb;               ncell = OL_CELLS; }
        else if (sb < LBLK + MBLK)  { pb = oM; lb = sb - LBLK;        ncell = OM_CELLS; }
        else                        { pb = oS; lb = sb - LBLK - MBLK; ncell = OS_CELLS; }

        const int o0 = lb * CPB + tid;
        const float* p0 = pb + (size_t)o0 * 8 + 4;      // conf of cell o0

        if (lb * CPB + CPB <= ncell) {
            // fast path: affine addresses base + k*8192B, no per-element guards
            float cv[SITER];
#pragma unroll
            for (int k = 0; k < SITER; k++)
                cv[k] = p0[(size_t)k * 2048];           // 256 cells * 8 floats
#pragma unroll
            for (int k = 0; k < SITER; k++)
                acc += -0.5f * safelog(1.0f - cv[k]);   // NOOBJ_SCALE*bce(conf,0)
        } else {
            // tail block (one per tensor): clamped loads, masked accumulate
            float cv[SITER];
#pragma unroll
            for (int k = 0; k < SITER; k++) {
                int o = o0 + k * 256;
                int oc = (o < ncell) ? o : (ncell - 1);
                cv[k] = pb[(size_t)oc * 8 + 4];
            }
#pragma unroll
            for (int k = 0; k < SITER; k++) {
                float t = -0.5f * safelog(1.0f - cv[k]);
                acc += ((o0 + k * 256) < ncell) ? t : 0.0f;
            }
        }
    }

    // wave butterfly (no barrier), then one LDS step + one per-block store
#pragma unroll
    for (int d = 1; d < 64; d <<= 1)
        acc += __shfl_xor(acc, d);
    if (l == 0) red4[w] = acc;
    __syncthreads();
    if (tid == 0)
        partials[u] = (red4[0] + red4[1]) + (red4[2] + red4[3]);
}

__global__ void final_reduce(const float* __restrict__ partials,
                             float* __restrict__ out) {
    __shared__ float red[256];
    const int tid = threadIdx.x;
    float acc = 0.0f;
    for (int i = tid; i < UNITS; i += 256) acc += partials[i];   // fixed order
    red[tid] = acc;
    __syncthreads();
#pragma unroll
    for (int s = 128; s > 0; s >>= 1) {
        if (tid < s) red[tid] += red[tid + s];
        __syncthreads();
    }
    if (tid == 0) out[0] = red[0] * (1.0f / (float)BATCH);
}

extern "C" void kernel_launch(void* const* d_in, const int* in_sizes, int n_in,
                              void* d_out, int out_size, void* d_ws, size_t ws_size,
                              hipStream_t stream) {
    const float* oL     = (const float*)d_in[0];
    const float* oM     = (const float*)d_in[1];
    const float* oS     = (const float*)d_in[2];
    const float* boxes  = (const float*)d_in[3];
    const int*   labels = (const int*)d_in[4];

    float* partials = (float*)d_ws;   // UNITS floats, fully overwritten each call

    fused_loss<<<UNITS, 256, 0, stream>>>(oL, oM, oS, boxes, labels, partials);
    final_reduce<<<1, 256, 0, stream>>>(partials, (float*)d_out);
}